// Round 3
// baseline (19079.668 us; speedup 1.0000x reference)
//
#include <hip/hip_runtime.h>
#include <cstddef>
#include <cstdint>

typedef unsigned short u16;

// Problem constants
constexpr int B_ = 512, T_ = 128, Z_ = 128, HE_ = 512, HD_ = 2048, NOUT_ = 123;

// ---------------- Workspace layout ----------------
// fp32 region (offsets in floats)
constexpr size_t OFF_HF   = 0;
constexpr size_t OFF_CF   = OFF_HF + (size_t)B_*HE_;
constexpr size_t OFF_HB   = OFF_CF + (size_t)B_*HE_;
constexpr size_t OFF_CB   = OFF_HB + (size_t)B_*HE_;
constexpr size_t OFF_HD   = OFF_CB + (size_t)B_*HE_;        // 512x2048 fp32 h (proj fallback)
constexpr size_t OFF_CD   = OFF_HD + (size_t)B_*HD_;
constexpr size_t OFF_ZW   = OFF_CD + (size_t)B_*HD_;        // 512x8192
constexpr size_t OFF_G    = OFF_ZW + (size_t)B_*4*HD_;      // scratch for init gemm (512x4096)
constexpr size_t OFF_HN   = OFF_G  + (size_t)B_*4*HD_;      // 512x1024
constexpr size_t OFF_ZMZL = OFF_HN + (size_t)B_*2*HE_;      // 512x256
constexpr size_t OFF_Z    = OFF_ZMZL + (size_t)B_*2*Z_;     // 512x128
constexpr size_t OFF_WX   = OFF_Z + (size_t)B_*Z_;          // 2x8192
constexpr size_t BASE_FLOATS = OFF_WX + (size_t)2*4*HD_;

// bf16 region (offsets in u16, relative to ws + BASE_FLOATS floats)
constexpr size_t SH_WDEC   = 0;                                // 8192x2048 gate-interleaved
constexpr size_t SH_WENCF  = SH_WDEC   + (size_t)4*HD_*HD_;    // 2048x512 gate-interleaved
constexpr size_t SH_WENCB  = SH_WENCF  + (size_t)4*HE_*HE_;
constexpr size_t SH_OUTW   = SH_WENCB  + (size_t)4*HE_*HE_;    // 128x2048 (rows>=123 zero)
constexpr size_t SH_HDEC0  = SH_OUTW   + (size_t)128*HD_;      // 512x2048 ping
constexpr size_t SH_HDEC1  = SH_HDEC0  + (size_t)B_*HD_;       // 512x2048 pong
constexpr size_t SH_HENCF0 = SH_HDEC1  + (size_t)B_*HD_;       // 512x512 (F0,B0 contiguous for memset)
constexpr size_t SH_HENCB0 = SH_HENCF0 + (size_t)B_*HE_;
constexpr size_t SH_HENCF1 = SH_HENCB0 + (size_t)B_*HE_;
constexpr size_t SH_HENCB1 = SH_HENCF1 + (size_t)B_*HE_;
constexpr size_t SH_HS     = SH_HENCB1 + (size_t)B_*HE_;       // optional 512x128x2048
constexpr size_t HS_SHORTS = (size_t)B_*T_*HD_;

__device__ __forceinline__ float sigm(float x) { return 1.f / (1.f + expf(-x)); }

__device__ __forceinline__ u16 f2bf(float x) {
    union { float f; uint32_t u; } v; v.f = x;
    uint32_t r = v.u + 0x7fffu + ((v.u >> 16) & 1u);
    return (u16)(r >> 16);
}

using bf16x8 = __attribute__((ext_vector_type(8))) short;
using f32x4  = __attribute__((ext_vector_type(4))) float;

__device__ __forceinline__ void gldl16(const void* g, void* l) {
    __builtin_amdgcn_global_load_lds(
        (const __attribute__((address_space(1))) unsigned int*)g,
        (__attribute__((address_space(3))) unsigned int*)l, 16, 0, 0);
}

// ================= Fused decoder step: g = h @ Wil^T, then LSTM pointwise in epilogue ====
// Wil gate-interleaved: row n' = 4*h + gate  (orig row gate*2048+h). Tile 64(M)x128(N'),
// grid (64 n-tiles fast, 8 m-tiles) = 512 blocks = 2/CU. 4 waves 1x4 in N, each 64x32.
__global__ __launch_bounds__(256) void dec_step_fused(
    const u16* __restrict__ hin, u16* __restrict__ hout,
    const u16* __restrict__ Wil, const float* __restrict__ zW,
    const float* __restrict__ data, const float* __restrict__ wx,
    float* __restrict__ h32, float* __restrict__ c32,
    u16* __restrict__ hs, int t)
{
    __shared__ __align__(16) u16 As[64 * 32];
    __shared__ __align__(16) u16 Ws[128 * 32];
    const int tid = threadIdx.x, lane = tid & 63, wave = tid >> 6;
    const int n0 = blockIdx.x * 128, m0 = blockIdx.y * 64;
    const int wn = wave << 5;
    const int fr = lane & 15, fk = lane >> 4;
    f32x4 acc[4][2] = {};

    const int sr = tid >> 2, sk = (tid & 3) << 3;
    const u16* ga  = hin + (size_t)(m0 + sr) * 2048 + sk;
    const u16* gw0 = Wil + (size_t)(n0 + sr) * 2048 + sk;
    const u16* gw1 = gw0 + (size_t)64 * 2048;
    u16* la  = As + tid * 8;
    u16* lw0 = Ws + tid * 8;
    u16* lw1 = lw0 + 2048;

    for (int k0 = 0; k0 < 2048; k0 += 32) {
        gldl16(ga + k0, la);
        gldl16(gw0 + k0, lw0);
        gldl16(gw1 + k0, lw1);
        __syncthreads();
        bf16x8 af[4], wf[2];
#pragma unroll
        for (int i = 0; i < 4; ++i)
            af[i] = *reinterpret_cast<const bf16x8*>(&As[(i * 16 + fr) * 32 + fk * 8]);
#pragma unroll
        for (int j = 0; j < 2; ++j)
            wf[j] = *reinterpret_cast<const bf16x8*>(&Ws[(wn + j * 16 + fr) * 32 + fk * 8]);
#pragma unroll
        for (int i = 0; i < 4; ++i)
#pragma unroll
            for (int j = 0; j < 2; ++j)
                acc[i][j] = __builtin_amdgcn_mfma_f32_16x16x32_bf16(af[i], wf[j], acc[i][j], 0, 0, 0);
        __syncthreads();
    }

    // epilogue: C/D layout col=lane&15, row=(lane>>4)*4+reg. gate = col&3 (tiles 4-aligned).
    const int cr = (lane >> 4) << 2, cc = lane & 15;
    const int gate = cc & 3, lb = lane & ~3;
#pragma unroll
    for (int i = 0; i < 4; ++i) {
#pragma unroll
        for (int r = 0; r < 4; ++r) {
            int m = m0 + i * 16 + cr + r;
            float x0 = data[m * 258 + t * 2 + 0];
            float x1 = data[m * 258 + t * 2 + 1];
#pragma unroll
            for (int j = 0; j < 2; ++j) {
                int np = n0 + wn + j * 16 + cc;
                int h = np >> 2;
                int no = gate * 2048 + h;               // original (non-interleaved) index
                float v = acc[i][j][r] + zW[(size_t)m * 8192 + no]
                          + x0 * wx[no] + x1 * wx[8192 + no];
                float gi = __shfl(v, lb);
                float gf = __shfl(v, lb | 1);
                float gg = __shfl(v, lb | 2);
                float go = __shfl(v, lb | 3);
                int o = m * 2048 + h;
                float c2 = sigm(gf) * c32[o] + sigm(gi) * tanhf(gg);
                float h2 = sigm(go) * tanhf(c2);
                if (gate == 0) h32[o] = h2;
                else if (gate == 1) c32[o] = c2;
                else if (gate == 2) hout[o] = f2bf(h2);
                else if (hs) hs[(size_t)m * (T_ * HD_) + (size_t)t * HD_ + h] = f2bf(h2);
            }
        }
    }
}

// ================= Fused encoder step (both dirs via blockIdx.z), masked by lengths =====
__global__ __launch_bounds__(256) void enc_step_fused(
    const u16* __restrict__ hFi, const u16* __restrict__ hBi,
    u16* __restrict__ hFo, u16* __restrict__ hBo,
    const u16* __restrict__ WF, const u16* __restrict__ WB,
    const float* __restrict__ WihF, const float* __restrict__ bF,
    const float* __restrict__ WihB, const float* __restrict__ bB,
    const float* __restrict__ data, const int* __restrict__ lengths,
    float* __restrict__ hF32, float* __restrict__ cF32,
    float* __restrict__ hB32, float* __restrict__ cB32, int t)
{
    __shared__ __align__(16) u16 As[64 * 32];
    __shared__ __align__(16) u16 Ws[128 * 32];
    const int dir = blockIdx.z;
    const u16* A   = dir ? hBi : hFi;
    const u16* Wm  = dir ? WB : WF;
    const float* Wih = dir ? WihB : WihF;
    const float* bia = dir ? bB : bF;
    const u16* hbi = dir ? hBi : hFi;
    u16* hbo       = dir ? hBo : hFo;
    float* h32     = dir ? hB32 : hF32;
    float* c32     = dir ? cB32 : cF32;

    const int tid = threadIdx.x, lane = tid & 63, wave = tid >> 6;
    const int n0 = blockIdx.x * 128, m0 = blockIdx.y * 64;
    const int wn = wave << 5;
    const int fr = lane & 15, fk = lane >> 4;
    f32x4 acc[4][2] = {};

    const int sr = tid >> 2, sk = (tid & 3) << 3;
    const u16* ga  = A  + (size_t)(m0 + sr) * 512 + sk;
    const u16* gw0 = Wm + (size_t)(n0 + sr) * 512 + sk;
    const u16* gw1 = gw0 + (size_t)64 * 512;
    u16* la  = As + tid * 8;
    u16* lw0 = Ws + tid * 8;
    u16* lw1 = lw0 + 2048;

    for (int k0 = 0; k0 < 512; k0 += 32) {
        gldl16(ga + k0, la);
        gldl16(gw0 + k0, lw0);
        gldl16(gw1 + k0, lw1);
        __syncthreads();
        bf16x8 af[4], wf[2];
#pragma unroll
        for (int i = 0; i < 4; ++i)
            af[i] = *reinterpret_cast<const bf16x8*>(&As[(i * 16 + fr) * 32 + fk * 8]);
#pragma unroll
        for (int j = 0; j < 2; ++j)
            wf[j] = *reinterpret_cast<const bf16x8*>(&Ws[(wn + j * 16 + fr) * 32 + fk * 8]);
#pragma unroll
        for (int i = 0; i < 4; ++i)
#pragma unroll
            for (int j = 0; j < 2; ++j)
                acc[i][j] = __builtin_amdgcn_mfma_f32_16x16x32_bf16(af[i], wf[j], acc[i][j], 0, 0, 0);
        __syncthreads();
    }

    const int cr = (lane >> 4) << 2, cc = lane & 15;
    const int gate = cc & 3, lb = lane & ~3;
#pragma unroll
    for (int i = 0; i < 4; ++i) {
#pragma unroll
        for (int r = 0; r < 4; ++r) {
            int m = m0 + i * 16 + cr + r;
            int L = lengths[m]; L = L < 1 ? 1 : (L > 128 ? 128 : L);
            bool act = (t < L);
            float x0 = 0.f, x1 = 0.f;
            if (act) {
                int row = dir ? (L - 1 - t) : t;
                x0 = data[m * 258 + (row + 1) * 2 + 0];
                x1 = data[m * 258 + (row + 1) * 2 + 1];
            }
#pragma unroll
            for (int j = 0; j < 2; ++j) {
                int np = n0 + wn + j * 16 + cc;
                int h = np >> 2;
                int no = gate * 512 + h;
                float v = acc[i][j][r] + bia[no] + x0 * Wih[2 * no] + x1 * Wih[2 * no + 1];
                float gi = __shfl(v, lb);
                float gf = __shfl(v, lb | 1);
                float gg = __shfl(v, lb | 2);
                float go = __shfl(v, lb | 3);
                int o = m * 512 + h;
                if (act) {
                    float c2 = sigm(gf) * c32[o] + sigm(gi) * tanhf(gg);
                    float h2 = sigm(go) * tanhf(c2);
                    if (gate == 0) h32[o] = h2;
                    else if (gate == 1) c32[o] = c2;
                    else if (gate == 2) hbo[o] = f2bf(h2);
                } else if (gate == 2) {
                    hbo[o] = hbi[o];        // carry old h into the pong buffer
                }
            }
        }
    }
}

// ================= plain bf16 MFMA GEMM (final projection): 128x128 tile =================
__device__ __forceinline__ void gemm_mfma_body(
    const u16* __restrict__ A, const u16* __restrict__ W,
    const float* __restrict__ bias, float* __restrict__ C,
    int Kd, int lda, int ldw, int ldc, int nmax, int m0, int n0)
{
    __shared__ __align__(16) u16 As[128 * 32];
    __shared__ __align__(16) u16 Ws[128 * 32];
    const int tid = threadIdx.x;
    const int lane = tid & 63;
    const int wave = tid >> 6;
    const int wm = (wave & 1) << 6, wn = (wave >> 1) << 6;
    const int fr = lane & 15, fk = lane >> 4;
    f32x4 acc[4][4] = {};

    const int sr = tid >> 2, sk = (tid & 3) << 3;
    const u16* ga0 = A + (size_t)(m0 + sr) * lda + sk;
    const u16* ga1 = ga0 + (size_t)64 * lda;
    const u16* gw0 = W + (size_t)(n0 + sr) * ldw + sk;
    const u16* gw1 = gw0 + (size_t)64 * ldw;
    u16* la0 = As + tid * 8;
    u16* la1 = la0 + 2048;
    u16* lw0 = Ws + tid * 8;
    u16* lw1 = lw0 + 2048;

    for (int k0 = 0; k0 < Kd; k0 += 32) {
        gldl16(ga0 + k0, la0);
        gldl16(ga1 + k0, la1);
        gldl16(gw0 + k0, lw0);
        gldl16(gw1 + k0, lw1);
        __syncthreads();
        bf16x8 af[4], wf[4];
#pragma unroll
        for (int i = 0; i < 4; ++i)
            af[i] = *reinterpret_cast<const bf16x8*>(&As[(wm + i * 16 + fr) * 32 + fk * 8]);
#pragma unroll
        for (int j = 0; j < 4; ++j)
            wf[j] = *reinterpret_cast<const bf16x8*>(&Ws[(wn + j * 16 + fr) * 32 + fk * 8]);
#pragma unroll
        for (int i = 0; i < 4; ++i)
#pragma unroll
            for (int j = 0; j < 4; ++j)
                acc[i][j] = __builtin_amdgcn_mfma_f32_16x16x32_bf16(af[i], wf[j], acc[i][j], 0, 0, 0);
        __syncthreads();
    }

    const int cr = (lane >> 4) << 2, cc = lane & 15;
#pragma unroll
    for (int j = 0; j < 4; ++j) {
        int n = n0 + wn + j * 16 + cc;
        if (n < nmax) {
            float bv = bias ? bias[n] : 0.f;
#pragma unroll
            for (int i = 0; i < 4; ++i) {
                int m = m0 + wm + i * 16 + cr;
                float* cp = C + (size_t)m * ldc + n;
#pragma unroll
                for (int r = 0; r < 4; ++r)
                    cp[(size_t)r * ldc] = acc[i][j][r] + bv;
            }
        }
    }
}

__global__ __launch_bounds__(256) void gemm_bf16_k(
    const u16* __restrict__ A, const u16* __restrict__ W,
    const float* __restrict__ bias, float* __restrict__ C,
    int Kd, int lda, int ldw, int ldc, int nmax)
{
    gemm_mfma_body(A, W, bias, C, Kd, lda, ldw, ldc, nmax,
                   blockIdx.x * 128, blockIdx.y * 128);
}

// ================= fp32 tiled GEMM (small latent GEMMs) =================
__device__ __forceinline__ void gemm_body(
    const float* __restrict__ A, const float* __restrict__ W,
    const float* __restrict__ bias, float* __restrict__ C,
    int N, int Kd, int lda, int aoff, int ldw, int woff,
    int ldc, int coff, int m0, int n0)
{
    __shared__ __align__(16) float As[16][68];
    __shared__ __align__(16) float Ws[16][68];
    const int tid = threadIdx.x;
    const int tx = tid & 15, ty = tid >> 4;
    float acc[4][4] = {};
    for (int k0 = 0; k0 < Kd; k0 += 16) {
#pragma unroll
        for (int i = 0; i < 4; ++i) {
            int e = tid + i * 256;
            int mm = e >> 4, kk = e & 15;
            As[kk][mm] = A[(size_t)(m0 + mm) * lda + aoff + k0 + kk];
        }
#pragma unroll
        for (int i = 0; i < 4; ++i) {
            int e = tid + i * 256;
            int nn = e >> 4, kk = e & 15;
            int n = n0 + nn;
            Ws[kk][nn] = (n < N) ? W[(size_t)n * ldw + woff + k0 + kk] : 0.f;
        }
        __syncthreads();
#pragma unroll
        for (int kk = 0; kk < 16; ++kk) {
            float4 a = *reinterpret_cast<const float4*>(&As[kk][ty * 4]);
            float4 w = *reinterpret_cast<const float4*>(&Ws[kk][tx * 4]);
            float av[4] = {a.x, a.y, a.z, a.w};
            float wv[4] = {w.x, w.y, w.z, w.w};
#pragma unroll
            for (int i = 0; i < 4; ++i)
#pragma unroll
                for (int j = 0; j < 4; ++j)
                    acc[i][j] = fmaf(av[i], wv[j], acc[i][j]);
        }
        __syncthreads();
    }
#pragma unroll
    for (int i = 0; i < 4; ++i) {
        int m = m0 + ty * 4 + i;
#pragma unroll
        for (int j = 0; j < 4; ++j) {
            int n = n0 + tx * 4 + j;
            if (n < N) {
                float v = acc[i][j];
                if (bias) v += bias[n];
                C[(size_t)m * ldc + coff + n] = v;
            }
        }
    }
}

__global__ __launch_bounds__(256) void gemm_k(
    const float* __restrict__ A, const float* __restrict__ W,
    const float* __restrict__ bias, float* __restrict__ C,
    int N, int Kd, int lda, int aoff, int ldw, int woff, int ldc, int coff)
{
    gemm_body(A, W, bias, C, N, Kd, lda, aoff, ldw, woff, ldc, coff,
              blockIdx.x * 64, blockIdx.y * 64);
}

// ================= conversion kernels =================
// decoder: dst[(4h+g)*2048+k] = bf16(src[(g*2048+h)*2048+k])
__global__ __launch_bounds__(256) void conv_wdec_il(
    const float* __restrict__ src, u16* __restrict__ dst)
{
    int row = blockIdx.x;                 // 8192 src rows
    int g = row >> 11, h = row & 2047;
    size_t so = (size_t)row * 2048, dofs = (size_t)(h * 4 + g) * 2048;
    for (int k = threadIdx.x; k < 2048; k += 256)
        dst[dofs + k] = f2bf(src[so + k]);
}

// encoder: dst[(4h+g)*512+k] = bf16(src[(g*512+h)*512+k]), both dirs
__global__ __launch_bounds__(256) void conv_wenc_il(
    const float* __restrict__ srcF, const float* __restrict__ srcB,
    u16* __restrict__ dstF, u16* __restrict__ dstB)
{
    int row = blockIdx.x & 2047;
    int dir = blockIdx.x >> 11;
    const float* s = dir ? srcB : srcF;
    u16* d = dir ? dstB : dstF;
    int g = row >> 9, h = row & 511;
    size_t so = (size_t)row * 512, dofs = (size_t)(h * 4 + g) * 512;
    for (int k = threadIdx.x; k < 512; k += 256)
        d[dofs + k] = f2bf(s[so + k]);
}

__global__ __launch_bounds__(256) void conv_outw(
    const float* __restrict__ w, u16* __restrict__ dst)
{
    int i = blockIdx.x * 256 + threadIdx.x;   // 128*2048
    int row = i >> 11, col = i & 2047;
    dst[i] = (row < NOUT_) ? f2bf(w[(size_t)row * HD_ + col]) : (u16)0;
}

// ================= small pointwise kernels =================
__global__ __launch_bounds__(256) void copy_hn(
    const float* __restrict__ hF, const float* __restrict__ hB, float* __restrict__ hn)
{
    int i = blockIdx.x * 256 + threadIdx.x;   // 512*1024
    int b = i >> 10, j = i & 1023;
    hn[i] = (j < 512) ? hF[b * 512 + j] : hB[b * 512 + j - 512];
}

__global__ __launch_bounds__(256) void point_z(
    const float* __restrict__ zmzl, const float* __restrict__ eps,
    float* __restrict__ ozm, float* __restrict__ ozl, float* __restrict__ z)
{
    int i = blockIdx.x * 256 + threadIdx.x;   // 512*128
    int b = i >> 7, j = i & 127;
    float zm = zmzl[b * 256 + j], zl = zmzl[b * 256 + 128 + j];
    ozm[i] = zm; ozl[i] = zl;
    z[i] = zm + expf(0.5f * zl) * eps[i];
}

__global__ __launch_bounds__(256) void point_init(
    const float* __restrict__ g, float* __restrict__ h, float* __restrict__ c,
    u16* __restrict__ hb)
{
    int i = blockIdx.x * 256 + threadIdx.x;   // 512*2048
    int b = i >> 11, n = i & 2047;
    float hv = tanhf(g[(size_t)b * 4096 + n]);
    h[i] = hv; hb[i] = f2bf(hv);
    c[i] = tanhf(g[(size_t)b * 4096 + 2048 + n]);
}

__global__ __launch_bounds__(256) void prep_wx(
    const float* __restrict__ Wih, float* __restrict__ wx)
{
    int j = blockIdx.x * 256 + threadIdx.x;   // 8192
    wx[j] = Wih[(size_t)j * 133];
    wx[8192 + j] = Wih[(size_t)j * 133 + 1];
}

// fallback per-step projection (only if ws too small for hs)
__global__ __launch_bounds__(256) void proj_step(
    const float* __restrict__ h, const float* __restrict__ out_W,
    const float* __restrict__ out_b, float* __restrict__ out, int t)
{
    __shared__ __align__(16) float sh[2048];
    int b = blockIdx.x;
    for (int i = threadIdx.x; i < 2048; i += 256) sh[i] = h[(size_t)b * 2048 + i];
    __syncthreads();
    int n = threadIdx.x >> 1, half = threadIdx.x & 1;
    if (n >= NOUT_) return;
    const float4* w4 = reinterpret_cast<const float4*>(out_W + (size_t)n * 2048 + half * 1024);
    const float4* h4 = reinterpret_cast<const float4*>(sh + half * 1024);
    float s = 0.f;
#pragma unroll 4
    for (int k = 0; k < 256; ++k) {
        float4 a = h4[k], w = w4[k];
        s += a.x * w.x + a.y * w.y + a.z * w.z + a.w * w.w;
    }
    s += __shfl_xor(s, 1);
    if (half == 0) out[(size_t)b * (T_ * NOUT_) + (size_t)t * NOUT_ + n] = s + out_b[n];
}

extern "C" void kernel_launch(void* const* d_in, const int* in_sizes, int n_in,
                              void* d_out, int out_size, void* d_ws, size_t ws_size,
                              hipStream_t stream)
{
    const float* data      = (const float*)d_in[0];
    const float* eps       = (const float*)d_in[1];
    const float* enc_Wih_f = (const float*)d_in[2];
    const float* enc_Whh_f = (const float*)d_in[3];
    const float* enc_b_f   = (const float*)d_in[4];
    const float* enc_Wih_b = (const float*)d_in[5];
    const float* enc_Whh_b = (const float*)d_in[6];
    const float* enc_b_b   = (const float*)d_in[7];
    const float* enc_out_W = (const float*)d_in[8];
    const float* enc_out_b = (const float*)d_in[9];
    const float* init_W    = (const float*)d_in[10];
    const float* init_b    = (const float*)d_in[11];
    const float* dec_Wih   = (const float*)d_in[12];
    const float* dec_Whh   = (const float*)d_in[13];
    const float* dec_b     = (const float*)d_in[14];
    const float* out_W     = (const float*)d_in[15];
    const float* out_b     = (const float*)d_in[16];
    const int*   lengths   = (const int*)d_in[17];

    float* ws  = (float*)d_ws;
    float* out = (float*)d_out;
    float* hF = ws + OFF_HF, *cF = ws + OFF_CF, *hB = ws + OFF_HB, *cB = ws + OFF_CB;
    float* hd = ws + OFF_HD, *cd = ws + OFF_CD;
    float* zW = ws + OFF_ZW, *g = ws + OFF_G, *hn = ws + OFF_HN;
    float* zmzl = ws + OFF_ZMZL, *z = ws + OFF_Z, *wx = ws + OFF_WX;
    u16* bw = (u16*)(ws + BASE_FLOATS);
    u16* wbDec  = bw + SH_WDEC, *wbEncF = bw + SH_WENCF, *wbEncB = bw + SH_WENCB;
    u16* wbOut  = bw + SH_OUTW;
    u16* hD0 = bw + SH_HDEC0,  *hD1 = bw + SH_HDEC1;
    u16* hEF0 = bw + SH_HENCF0, *hEB0 = bw + SH_HENCB0;
    u16* hEF1 = bw + SH_HENCF1, *hEB1 = bw + SH_HENCB1;
    float* ozm = out + (size_t)B_ * T_ * NOUT_;
    float* ozl = ozm + (size_t)B_ * Z_;

    // weight conversions (every call: ws is re-poisoned)
    conv_wdec_il<<<8192, 256, 0, stream>>>(dec_Whh, wbDec);
    conv_wenc_il<<<4096, 256, 0, stream>>>(enc_Whh_f, enc_Whh_b, wbEncF, wbEncB);
    conv_outw<<<1024, 256, 0, stream>>>(out_W, wbOut);

    // zero-init encoder fp32 h/c and bf16 ping buffers (F0,B0 contiguous)
    hipMemsetAsync(ws, 0, (size_t)4 * B_ * HE_ * sizeof(float), stream);
    hipMemsetAsync(hEF0, 0, (size_t)2 * B_ * HE_ * sizeof(u16), stream);

    // ---- encoder: 128 fused steps, both directions, ping-pong bf16 h
    for (int t = 0; t < T_; ++t) {
        const u16* fi = (t & 1) ? hEF1 : hEF0;
        const u16* bi = (t & 1) ? hEB1 : hEB0;
        u16* fo = (t & 1) ? hEF0 : hEF1;
        u16* bo = (t & 1) ? hEB0 : hEB1;
        enc_step_fused<<<dim3(16, 8, 2), 256, 0, stream>>>(
            fi, bi, fo, bo, wbEncF, wbEncB,
            enc_Wih_f, enc_b_f, enc_Wih_b, enc_b_b,
            data, lengths, hF, cF, hB, cB, t);
    }

    // ---- latent + decoder init (fp32, tiny)
    copy_hn<<<2048, 256, 0, stream>>>(hF, hB, hn);
    gemm_k<<<dim3(8, 4), 256, 0, stream>>>(hn, enc_out_W, enc_out_b, zmzl,
                                           256, 1024, 1024, 0, 1024, 0, 256, 0);
    point_z<<<256, 256, 0, stream>>>(zmzl, eps, ozm, ozl, z);
    gemm_k<<<dim3(8, 64), 256, 0, stream>>>(z, init_W, init_b, g,
                                            4096, 128, 128, 0, 128, 0, 4096, 0);
    point_init<<<4096, 256, 0, stream>>>(g, hd, cd, hD0);
    gemm_k<<<dim3(8, 128), 256, 0, stream>>>(z, dec_Wih, dec_b, zW,
                                             8192, 128, 128, 0, 133, 5, 8192, 0);
    prep_wx<<<32, 256, 0, stream>>>(dec_Wih, wx);

    // ---- decoder: 128 fused steps
    bool big = ws_size >= BASE_FLOATS * sizeof(float) + (SH_HS + HS_SHORTS) * sizeof(u16);
    u16* hs = big ? (bw + SH_HS) : nullptr;
    for (int t = 0; t < T_; ++t) {
        const u16* hi = (t & 1) ? hD1 : hD0;
        u16* ho = (t & 1) ? hD0 : hD1;
        dec_step_fused<<<dim3(64, 8), 256, 0, stream>>>(
            hi, ho, wbDec, zW, data, wx, hd, cd, hs, t);
        if (!big) proj_step<<<512, 256, 0, stream>>>(hd, out_W, out_b, out, t);
    }
    if (big) {
        // params = hs @ out_W^T + out_b  (M=65536, N=123 padded to 128, K=2048)
        gemm_bf16_k<<<dim3(512, 1), 256, 0, stream>>>(hs, wbOut, out_b, out,
                                                      2048, 2048, 2048, 123, 123);
    }
}

// Round 4
// 15508.862 us; speedup vs baseline: 1.2302x; 1.2302x over previous
//
#include <hip/hip_runtime.h>
#include <cstddef>
#include <cstdint>

typedef unsigned short u16;

// Problem constants
constexpr int B_ = 512, T_ = 128, Z_ = 128, HE_ = 512, HD_ = 2048, NOUT_ = 123;

// ---------------- Workspace layout ----------------
// fp32 region (offsets in floats)
constexpr size_t OFF_HF   = 0;
constexpr size_t OFF_CF   = OFF_HF + (size_t)B_*HE_;
constexpr size_t OFF_HB   = OFF_CF + (size_t)B_*HE_;
constexpr size_t OFF_CB   = OFF_HB + (size_t)B_*HE_;
constexpr size_t OFF_HD   = OFF_CB + (size_t)B_*HE_;        // 512x2048
constexpr size_t OFF_CD   = OFF_HD + (size_t)B_*HD_;
constexpr size_t OFF_ZW   = OFF_CD + (size_t)B_*HD_;        // 512x8192
constexpr size_t OFF_G    = OFF_ZW + (size_t)B_*4*HD_;      // 512x8192 scratch
constexpr size_t OFF_HN   = OFF_G  + (size_t)B_*4*HD_;      // 512x1024
constexpr size_t OFF_ZMZL = OFF_HN + (size_t)B_*2*HE_;      // 512x256
constexpr size_t OFF_Z    = OFF_ZMZL + (size_t)B_*2*Z_;     // 512x128
constexpr size_t OFF_WX   = OFF_Z + (size_t)B_*Z_;          // 2x8192
constexpr size_t BASE_FLOATS = OFF_WX + (size_t)2*4*HD_;

// bf16 region (offsets in u16, relative to ws + BASE_FLOATS floats)
constexpr size_t SH_WDEC  = 0;                               // 8192x2048
constexpr size_t SH_WENCF = SH_WDEC  + (size_t)4*HD_*HD_;    // 2048x512
constexpr size_t SH_WENCB = SH_WENCF + (size_t)4*HE_*HE_;
constexpr size_t SH_OUTW  = SH_WENCB + (size_t)4*HE_*HE_;    // 128x2048 (rows>=123 zero)
constexpr size_t SH_HDEC  = SH_OUTW  + (size_t)128*HD_;      // 512x2048
constexpr size_t SH_HENCF = SH_HDEC  + (size_t)B_*HD_;       // 512x512
constexpr size_t SH_HENCB = SH_HENCF + (size_t)B_*HE_;       // 512x512 (contiguous with F)
constexpr size_t SH_HS    = SH_HENCB + (size_t)B_*HE_;       // optional 512x128x2048
constexpr size_t HS_SHORTS = (size_t)B_*T_*HD_;

__device__ __forceinline__ float sigm(float x) { return 1.f / (1.f + expf(-x)); }

__device__ __forceinline__ u16 f2bf(float x) {
    union { float f; uint32_t u; } v; v.f = x;
    uint32_t r = v.u + 0x7fffu + ((v.u >> 16) & 1u);
    return (u16)(r >> 16);
}

using bf16x8 = __attribute__((ext_vector_type(8))) short;
using f32x4  = __attribute__((ext_vector_type(4))) float;

__device__ __forceinline__ void gldl16(const void* g, void* l) {
    __builtin_amdgcn_global_load_lds(
        (const __attribute__((address_space(1))) unsigned int*)g,
        (__attribute__((address_space(3))) unsigned int*)l, 16, 0, 0);
}

// ================= Decoder GEMM: g = h @ Wdec^T.  64(M)x128(N) tile, BK=32. ============
// grid (64 n-tiles FAST, 8 m-tiles) = 512 blocks = 2/CU; XCD = blockIdx.x % 8 -> each XCD
// serves 8 n-tiles = 4 MB of W, L2-resident across m-tiles and all 128 steps.
__global__ __launch_bounds__(256) void gemm_dec64(
    const u16* __restrict__ A, const u16* __restrict__ W, float* __restrict__ C)
{
    __shared__ __align__(16) u16 As[64 * 32];
    __shared__ __align__(16) u16 Ws[128 * 32];
    const int tid = threadIdx.x, lane = tid & 63, wave = tid >> 6;
    const int n0 = blockIdx.x * 128, m0 = blockIdx.y * 64;
    const int wn = wave << 5;
    const int fr = lane & 15, fk = lane >> 4;
    f32x4 acc[4][2] = {};

    const int sr = tid >> 2, sk = (tid & 3) << 3;
    const u16* ga  = A + (size_t)(m0 + sr) * 2048 + sk;
    const u16* gw0 = W + (size_t)(n0 + sr) * 2048 + sk;
    const u16* gw1 = gw0 + (size_t)64 * 2048;
    u16* la  = As + tid * 8;
    u16* lw0 = Ws + tid * 8;
    u16* lw1 = lw0 + 2048;

    for (int k0 = 0; k0 < 2048; k0 += 32) {
        gldl16(ga + k0, la);
        gldl16(gw0 + k0, lw0);
        gldl16(gw1 + k0, lw1);
        __syncthreads();
        bf16x8 af[4], wf[2];
#pragma unroll
        for (int i = 0; i < 4; ++i)
            af[i] = *reinterpret_cast<const bf16x8*>(&As[(i * 16 + fr) * 32 + fk * 8]);
#pragma unroll
        for (int j = 0; j < 2; ++j)
            wf[j] = *reinterpret_cast<const bf16x8*>(&Ws[(wn + j * 16 + fr) * 32 + fk * 8]);
#pragma unroll
        for (int i = 0; i < 4; ++i)
#pragma unroll
            for (int j = 0; j < 2; ++j)
                acc[i][j] = __builtin_amdgcn_mfma_f32_16x16x32_bf16(af[i], wf[j], acc[i][j], 0, 0, 0);
        __syncthreads();
    }

    // C/D layout: col = lane&15, row = (lane>>4)*4 + reg
    const int cr = (lane >> 4) << 2, cc = lane & 15;
#pragma unroll
    for (int i = 0; i < 4; ++i) {
#pragma unroll
        for (int j = 0; j < 2; ++j) {
            int n = n0 + wn + j * 16 + cc;
            float* cp = C + (size_t)(m0 + i * 16 + cr) * 8192 + n;
#pragma unroll
            for (int r = 0; r < 4; ++r)
                cp[(size_t)r * 8192] = acc[i][j][r];
        }
    }
}

// ================= plain bf16 MFMA GEMM, 128x128 tile (encoder + projection) ============
__device__ __forceinline__ void gemm_mfma_body(
    const u16* __restrict__ A, const u16* __restrict__ W,
    const float* __restrict__ bias, float* __restrict__ C,
    int Kd, int lda, int ldw, int ldc, int nmax, int m0, int n0)
{
    __shared__ __align__(16) u16 As[128 * 32];
    __shared__ __align__(16) u16 Ws[128 * 32];
    const int tid = threadIdx.x;
    const int lane = tid & 63;
    const int wave = tid >> 6;
    const int wm = (wave & 1) << 6, wn = (wave >> 1) << 6;
    const int fr = lane & 15, fk = lane >> 4;
    f32x4 acc[4][4] = {};

    const int sr = tid >> 2, sk = (tid & 3) << 3;
    const u16* ga0 = A + (size_t)(m0 + sr) * lda + sk;
    const u16* ga1 = ga0 + (size_t)64 * lda;
    const u16* gw0 = W + (size_t)(n0 + sr) * ldw + sk;
    const u16* gw1 = gw0 + (size_t)64 * ldw;
    u16* la0 = As + tid * 8;
    u16* la1 = la0 + 2048;
    u16* lw0 = Ws + tid * 8;
    u16* lw1 = lw0 + 2048;

    for (int k0 = 0; k0 < Kd; k0 += 32) {
        gldl16(ga0 + k0, la0);
        gldl16(ga1 + k0, la1);
        gldl16(gw0 + k0, lw0);
        gldl16(gw1 + k0, lw1);
        __syncthreads();
        bf16x8 af[4], wf[4];
#pragma unroll
        for (int i = 0; i < 4; ++i)
            af[i] = *reinterpret_cast<const bf16x8*>(&As[(wm + i * 16 + fr) * 32 + fk * 8]);
#pragma unroll
        for (int j = 0; j < 4; ++j)
            wf[j] = *reinterpret_cast<const bf16x8*>(&Ws[(wn + j * 16 + fr) * 32 + fk * 8]);
#pragma unroll
        for (int i = 0; i < 4; ++i)
#pragma unroll
            for (int j = 0; j < 4; ++j)
                acc[i][j] = __builtin_amdgcn_mfma_f32_16x16x32_bf16(af[i], wf[j], acc[i][j], 0, 0, 0);
        __syncthreads();
    }

    const int cr = (lane >> 4) << 2, cc = lane & 15;
#pragma unroll
    for (int j = 0; j < 4; ++j) {
        int n = n0 + wn + j * 16 + cc;
        if (n < nmax) {
            float bv = bias ? bias[n] : 0.f;
#pragma unroll
            for (int i = 0; i < 4; ++i) {
                int m = m0 + wm + i * 16 + cr;
                float* cp = C + (size_t)m * ldc + n;
#pragma unroll
                for (int r = 0; r < 4; ++r)
                    cp[(size_t)r * ldc] = acc[i][j][r] + bv;
            }
        }
    }
}

__global__ __launch_bounds__(256) void gemm_bf16_k(
    const u16* __restrict__ A, const u16* __restrict__ W,
    const float* __restrict__ bias, float* __restrict__ C,
    int Kd, int lda, int ldw, int ldc, int nmax)
{
    gemm_mfma_body(A, W, bias, C, Kd, lda, ldw, ldc, nmax,
                   blockIdx.x * 128, blockIdx.y * 128);
}

// Encoder recurrent GEMM, both directions via blockIdx.z; n-tile FAST in blockIdx.x.
__global__ __launch_bounds__(256) void gemm_enc_mfma(
    const u16* __restrict__ hF, const u16* __restrict__ hB,
    const u16* __restrict__ Wf, const u16* __restrict__ Wb,
    float* __restrict__ g)
{
    const u16* A = blockIdx.z ? hB : hF;
    const u16* W = blockIdx.z ? Wb : Wf;
    float* C = g + (size_t)blockIdx.z * ((size_t)B_ * 4 * HE_);
    gemm_mfma_body(A, W, nullptr, C, HE_, HE_, HE_, 4 * HE_, 4 * HE_,
                   blockIdx.y * 128, blockIdx.x * 128);
}

// ================= fp32 tiled GEMM (small latent GEMMs) =================
__device__ __forceinline__ void gemm_body(
    const float* __restrict__ A, const float* __restrict__ W,
    const float* __restrict__ bias, float* __restrict__ C,
    int N, int Kd, int lda, int aoff, int ldw, int woff,
    int ldc, int coff, int m0, int n0)
{
    __shared__ __align__(16) float As[16][68];
    __shared__ __align__(16) float Ws[16][68];
    const int tid = threadIdx.x;
    const int tx = tid & 15, ty = tid >> 4;
    float acc[4][4] = {};
    for (int k0 = 0; k0 < Kd; k0 += 16) {
#pragma unroll
        for (int i = 0; i < 4; ++i) {
            int e = tid + i * 256;
            int mm = e >> 4, kk = e & 15;
            As[kk][mm] = A[(size_t)(m0 + mm) * lda + aoff + k0 + kk];
        }
#pragma unroll
        for (int i = 0; i < 4; ++i) {
            int e = tid + i * 256;
            int nn = e >> 4, kk = e & 15;
            int n = n0 + nn;
            Ws[kk][nn] = (n < N) ? W[(size_t)n * ldw + woff + k0 + kk] : 0.f;
        }
        __syncthreads();
#pragma unroll
        for (int kk = 0; kk < 16; ++kk) {
            float4 a = *reinterpret_cast<const float4*>(&As[kk][ty * 4]);
            float4 w = *reinterpret_cast<const float4*>(&Ws[kk][tx * 4]);
            float av[4] = {a.x, a.y, a.z, a.w};
            float wv[4] = {w.x, w.y, w.z, w.w};
#pragma unroll
            for (int i = 0; i < 4; ++i)
#pragma unroll
                for (int j = 0; j < 4; ++j)
                    acc[i][j] = fmaf(av[i], wv[j], acc[i][j]);
        }
        __syncthreads();
    }
#pragma unroll
    for (int i = 0; i < 4; ++i) {
        int m = m0 + ty * 4 + i;
#pragma unroll
        for (int j = 0; j < 4; ++j) {
            int n = n0 + tx * 4 + j;
            if (n < N) {
                float v = acc[i][j];
                if (bias) v += bias[n];
                C[(size_t)m * ldc + coff + n] = v;
            }
        }
    }
}

__global__ __launch_bounds__(256) void gemm_k(
    const float* __restrict__ A, const float* __restrict__ W,
    const float* __restrict__ bias, float* __restrict__ C,
    int N, int Kd, int lda, int aoff, int ldw, int woff, int ldc, int coff)
{
    gemm_body(A, W, bias, C, N, Kd, lda, aoff, ldw, woff, ldc, coff,
              blockIdx.x * 64, blockIdx.y * 64);
}

// ================= conversion kernels =================
__global__ __launch_bounds__(256) void conv_bf16(
    const float* __restrict__ src, u16* __restrict__ dst, int n)
{
    int stride = gridDim.x * 256;
    for (int i = blockIdx.x * 256 + threadIdx.x; i < n; i += stride)
        dst[i] = f2bf(src[i]);
}

__global__ __launch_bounds__(256) void conv_outw(
    const float* __restrict__ w, u16* __restrict__ dst)
{
    int i = blockIdx.x * 256 + threadIdx.x;   // 128*2048
    int row = i >> 11, col = i & 2047;
    dst[i] = (row < NOUT_) ? f2bf(w[(size_t)row * HD_ + col]) : (u16)0;
}

// ================= pointwise kernels =================
__global__ __launch_bounds__(256) void point_enc(
    const float* __restrict__ g, const float* __restrict__ data,
    const float* __restrict__ Wih_f, const float* __restrict__ bf,
    const float* __restrict__ Wih_b, const float* __restrict__ bb,
    const int* __restrict__ lengths,
    float* __restrict__ hF, float* __restrict__ cF,
    float* __restrict__ hB, float* __restrict__ cB,
    u16* __restrict__ hFb, u16* __restrict__ hBb, int t)
{
    int idx = blockIdx.x * 256 + threadIdx.x;   // 2*512*512
    int dir = idx >> 18;
    int r = idx & ((1 << 18) - 1);
    int b = r >> 9, n = r & 511;
    int L = lengths[b]; L = L < 1 ? 1 : (L > 128 ? 128 : L);
    if (t >= L) return;  // masked step: h,c unchanged
    const float* gp = g + (size_t)dir * ((size_t)B_ * 4 * HE_) + (size_t)b * (4 * HE_);
    float gi = gp[n], gf = gp[HE_ + n], gg = gp[2 * HE_ + n], go = gp[3 * HE_ + n];
    int row = dir ? (L - 1 - t) : t;
    float x0 = data[b * 258 + (row + 1) * 2 + 0];
    float x1 = data[b * 258 + (row + 1) * 2 + 1];
    const float* Wih = dir ? Wih_b : Wih_f;
    const float* bias = dir ? bb : bf;
    gi += bias[n]          + x0 * Wih[2 * n]              + x1 * Wih[2 * n + 1];
    gf += bias[HE_ + n]    + x0 * Wih[2 * (HE_ + n)]      + x1 * Wih[2 * (HE_ + n) + 1];
    gg += bias[2*HE_ + n]  + x0 * Wih[2 * (2*HE_ + n)]    + x1 * Wih[2 * (2*HE_ + n) + 1];
    go += bias[3*HE_ + n]  + x0 * Wih[2 * (3*HE_ + n)]    + x1 * Wih[2 * (3*HE_ + n) + 1];
    float* h = dir ? hB : hF;
    float* c = dir ? cB : cF;
    u16* hb = dir ? hBb : hFb;
    int o = b * HE_ + n;
    float c2 = sigm(gf) * c[o] + sigm(gi) * tanhf(gg);
    float h2 = sigm(go) * tanhf(c2);
    h[o] = h2; c[o] = c2; hb[o] = f2bf(h2);
}

__global__ __launch_bounds__(256) void copy_hn(
    const float* __restrict__ hF, const float* __restrict__ hB, float* __restrict__ hn)
{
    int i = blockIdx.x * 256 + threadIdx.x;   // 512*1024
    int b = i >> 10, j = i & 1023;
    hn[i] = (j < 512) ? hF[b * 512 + j] : hB[b * 512 + j - 512];
}

__global__ __launch_bounds__(256) void point_z(
    const float* __restrict__ zmzl, const float* __restrict__ eps,
    float* __restrict__ ozm, float* __restrict__ ozl, float* __restrict__ z)
{
    int i = blockIdx.x * 256 + threadIdx.x;   // 512*128
    int b = i >> 7, j = i & 127;
    float zm = zmzl[b * 256 + j], zl = zmzl[b * 256 + 128 + j];
    ozm[i] = zm; ozl[i] = zl;
    z[i] = zm + expf(0.5f * zl) * eps[i];
}

__global__ __launch_bounds__(256) void point_init(
    const float* __restrict__ g, float* __restrict__ h, float* __restrict__ c,
    u16* __restrict__ hb)
{
    int i = blockIdx.x * 256 + threadIdx.x;   // 512*2048
    int b = i >> 11, n = i & 2047;
    float hv = tanhf(g[(size_t)b * 4096 + n]);
    h[i] = hv; hb[i] = f2bf(hv);
    c[i] = tanhf(g[(size_t)b * 4096 + 2048 + n]);
}

__global__ __launch_bounds__(256) void prep_wx(
    const float* __restrict__ Wih, float* __restrict__ wx)
{
    int j = blockIdx.x * 256 + threadIdx.x;   // 8192
    wx[j] = Wih[(size_t)j * 133];
    wx[8192 + j] = Wih[(size_t)j * 133 + 1];
}

__global__ __launch_bounds__(256) void point_dec(
    const float* __restrict__ g, const float* __restrict__ zW,
    const float* __restrict__ data, const float* __restrict__ wx,
    float* __restrict__ h, float* __restrict__ c,
    u16* __restrict__ hb, u16* __restrict__ hs, int t)
{
    int idx = blockIdx.x * 256 + threadIdx.x;  // 512*2048
    int b = idx >> 11, n = idx & 2047;
    float x0 = data[b * 258 + t * 2 + 0];
    float x1 = data[b * 258 + t * 2 + 1];
    const float* gp = g + (size_t)b * 8192;
    const float* zp = zW + (size_t)b * 8192;
    int j0 = n, j1 = 2048 + n, j2 = 4096 + n, j3 = 6144 + n;
    float gi = gp[j0] + zp[j0] + x0 * wx[j0] + x1 * wx[8192 + j0];
    float gf = gp[j1] + zp[j1] + x0 * wx[j1] + x1 * wx[8192 + j1];
    float gg = gp[j2] + zp[j2] + x0 * wx[j2] + x1 * wx[8192 + j2];
    float go = gp[j3] + zp[j3] + x0 * wx[j3] + x1 * wx[8192 + j3];
    float c2 = sigm(gf) * c[idx] + sigm(gi) * tanhf(gg);
    float h2 = sigm(go) * tanhf(c2);
    h[idx] = h2; c[idx] = c2;
    u16 hv = f2bf(h2);
    hb[idx] = hv;
    if (hs) hs[(size_t)b * (T_ * HD_) + (size_t)t * HD_ + n] = hv;
}

// Per-step output projection fallback (fp32): params[b,t,:] = h[b,:] @ out_W^T + out_b
__global__ __launch_bounds__(256) void proj_step(
    const float* __restrict__ h, const float* __restrict__ out_W,
    const float* __restrict__ out_b, float* __restrict__ out, int t)
{
    __shared__ __align__(16) float sh[2048];
    int b = blockIdx.x;
    for (int i = threadIdx.x; i < 2048; i += 256) sh[i] = h[(size_t)b * 2048 + i];
    __syncthreads();
    int n = threadIdx.x >> 1, half = threadIdx.x & 1;
    if (n >= NOUT_) return;
    const float4* w4 = reinterpret_cast<const float4*>(out_W + (size_t)n * 2048 + half * 1024);
    const float4* h4 = reinterpret_cast<const float4*>(sh + half * 1024);
    float s = 0.f;
#pragma unroll 4
    for (int k = 0; k < 256; ++k) {
        float4 a = h4[k], w = w4[k];
        s += a.x * w.x + a.y * w.y + a.z * w.z + a.w * w.w;
    }
    s += __shfl_xor(s, 1);
    if (half == 0) out[(size_t)b * (T_ * NOUT_) + (size_t)t * NOUT_ + n] = s + out_b[n];
}

extern "C" void kernel_launch(void* const* d_in, const int* in_sizes, int n_in,
                              void* d_out, int out_size, void* d_ws, size_t ws_size,
                              hipStream_t stream)
{
    const float* data      = (const float*)d_in[0];
    const float* eps       = (const float*)d_in[1];
    const float* enc_Wih_f = (const float*)d_in[2];
    const float* enc_Whh_f = (const float*)d_in[3];
    const float* enc_b_f   = (const float*)d_in[4];
    const float* enc_Wih_b = (const float*)d_in[5];
    const float* enc_Whh_b = (const float*)d_in[6];
    const float* enc_b_b   = (const float*)d_in[7];
    const float* enc_out_W = (const float*)d_in[8];
    const float* enc_out_b = (const float*)d_in[9];
    const float* init_W    = (const float*)d_in[10];
    const float* init_b    = (const float*)d_in[11];
    const float* dec_Wih   = (const float*)d_in[12];
    const float* dec_Whh   = (const float*)d_in[13];
    const float* dec_b     = (const float*)d_in[14];
    const float* out_W     = (const float*)d_in[15];
    const float* out_b     = (const float*)d_in[16];
    const int*   lengths   = (const int*)d_in[17];

    float* ws  = (float*)d_ws;
    float* out = (float*)d_out;
    float* hF = ws + OFF_HF, *cF = ws + OFF_CF, *hB = ws + OFF_HB, *cB = ws + OFF_CB;
    float* hd = ws + OFF_HD, *cd = ws + OFF_CD;
    float* zW = ws + OFF_ZW, *g = ws + OFF_G, *hn = ws + OFF_HN;
    float* zmzl = ws + OFF_ZMZL, *z = ws + OFF_Z, *wx = ws + OFF_WX;
    u16* bw = (u16*)(ws + BASE_FLOATS);
    u16* wbDec = bw + SH_WDEC, *wbEncF = bw + SH_WENCF, *wbEncB = bw + SH_WENCB;
    u16* wbOut = bw + SH_OUTW;
    u16* hbDec = bw + SH_HDEC, *hbEncF = bw + SH_HENCF, *hbEncB = bw + SH_HENCB;
    float* ozm = out + (size_t)B_ * T_ * NOUT_;
    float* ozl = ozm + (size_t)B_ * Z_;

    // weight conversions (every call: ws is re-poisoned)
    conv_bf16<<<4096, 256, 0, stream>>>(dec_Whh, wbDec, 4 * HD_ * HD_);
    conv_bf16<<<1024, 256, 0, stream>>>(enc_Whh_f, wbEncF, 4 * HE_ * HE_);
    conv_bf16<<<1024, 256, 0, stream>>>(enc_Whh_b, wbEncB, 4 * HE_ * HE_);
    conv_outw<<<1024, 256, 0, stream>>>(out_W, wbOut);

    // zero-init encoder h/c (fp32) and bf16 h (F and B contiguous)
    hipMemsetAsync(ws, 0, (size_t)4 * B_ * HE_ * sizeof(float), stream);
    hipMemsetAsync(hbEncF, 0, (size_t)2 * B_ * HE_ * sizeof(u16), stream);

    // ---- encoder: 128 steps (n-tile fast in blockIdx.x for XCD L2 locality)
    for (int t = 0; t < T_; ++t) {
        gemm_enc_mfma<<<dim3(16, 4, 2), 256, 0, stream>>>(hbEncF, hbEncB, wbEncF, wbEncB, g);
        point_enc<<<2048, 256, 0, stream>>>(g, data, enc_Wih_f, enc_b_f, enc_Wih_b, enc_b_b,
                                            lengths, hF, cF, hB, cB, hbEncF, hbEncB, t);
    }

    // ---- latent + decoder init (fp32, tiny)
    copy_hn<<<2048, 256, 0, stream>>>(hF, hB, hn);
    gemm_k<<<dim3(8, 4), 256, 0, stream>>>(hn, enc_out_W, enc_out_b, zmzl,
                                           256, 1024, 1024, 0, 1024, 0, 256, 0);
    point_z<<<256, 256, 0, stream>>>(zmzl, eps, ozm, ozl, z);
    gemm_k<<<dim3(8, 64), 256, 0, stream>>>(z, init_W, init_b, g,
                                            4096, 128, 128, 0, 128, 0, 4096, 0);
    point_init<<<4096, 256, 0, stream>>>(g, hd, cd, hbDec);
    gemm_k<<<dim3(8, 128), 256, 0, stream>>>(z, dec_Wih, dec_b, zW,
                                             8192, 128, 128, 0, 133, 5, 8192, 0);
    prep_wx<<<32, 256, 0, stream>>>(dec_Wih, wx);

    // ---- decoder: 128 steps (64x128 tile, n-fast grid: 512 blocks = 2/CU)
    bool big = ws_size >= BASE_FLOATS * sizeof(float) + (SH_HS + HS_SHORTS) * sizeof(u16);
    u16* hs = big ? (bw + SH_HS) : nullptr;
    for (int t = 0; t < T_; ++t) {
        gemm_dec64<<<dim3(64, 8), 256, 0, stream>>>(hbDec, wbDec, g);
        point_dec<<<4096, 256, 0, stream>>>(g, zW, data, wx, hd, cd, hbDec, hs, t);
        if (!big) proj_step<<<512, 256, 0, stream>>>(hd, out_W, out_b, out, t);
    }
    if (big) {
        // params = hs @ out_W^T + out_b  (M=65536, N=123 padded to 128, K=2048)
        gemm_bf16_k<<<dim3(512, 1), 256, 0, stream>>>(hs, wbOut, out_b, out,
                                                      2048, 2048, 2048, 123, 123);
    }
}

// Round 5
// 15429.243 us; speedup vs baseline: 1.2366x; 1.0052x over previous
//
#include <hip/hip_runtime.h>
#include <hip/hip_cooperative_groups.h>
#include <cstddef>
#include <cstdint>

typedef unsigned short u16;
namespace cg = cooperative_groups;

// Problem constants
constexpr int B_ = 512, T_ = 128, Z_ = 128, HE_ = 512, HD_ = 2048, NOUT_ = 123;

// ---------------- Workspace layout ----------------
// fp32 region (offsets in floats)
constexpr size_t OFF_HF   = 0;
constexpr size_t OFF_CF   = OFF_HF + (size_t)B_*HE_;
constexpr size_t OFF_HB   = OFF_CF + (size_t)B_*HE_;
constexpr size_t OFF_CB   = OFF_HB + (size_t)B_*HE_;
constexpr size_t OFF_HD   = OFF_CB + (size_t)B_*HE_;        // 512x2048 (fallback only)
constexpr size_t OFF_CD   = OFF_HD + (size_t)B_*HD_;
constexpr size_t OFF_ZW   = OFF_CD + (size_t)B_*HD_;        // 512x8192
constexpr size_t OFF_G    = OFF_ZW + (size_t)B_*4*HD_;      // 512x8192: g (fallback) / zwil (persistent)
constexpr size_t OFF_HN   = OFF_G  + (size_t)B_*4*HD_;      // 512x1024; head reused as enc ihb (12288 f)
constexpr size_t OFF_ZMZL = OFF_HN + (size_t)B_*2*HE_;      // 512x256
constexpr size_t OFF_Z    = OFF_ZMZL + (size_t)B_*2*Z_;     // 512x128
constexpr size_t OFF_WX   = OFF_Z + (size_t)B_*Z_;          // 2x8192 (wx plain or interleaved)
constexpr size_t BASE_FLOATS = OFF_WX + (size_t)2*4*HD_;

// bf16 region (offsets in u16, relative to ws + BASE_FLOATS floats)
constexpr size_t SH_WDEC   = 0;                                // 8192x2048
constexpr size_t SH_WENCF  = SH_WDEC   + (size_t)4*HD_*HD_;    // 2048x512
constexpr size_t SH_WENCB  = SH_WENCF  + (size_t)4*HE_*HE_;
constexpr size_t SH_OUTW   = SH_WENCB  + (size_t)4*HE_*HE_;    // 128x2048 (rows>=123 zero)
constexpr size_t SH_HDEC0  = SH_OUTW   + (size_t)128*HD_;      // 512x2048 ping
constexpr size_t SH_HDEC1  = SH_HDEC0  + (size_t)B_*HD_;       // 512x2048 pong
constexpr size_t SH_HENCF0 = SH_HDEC1  + (size_t)B_*HD_;       // 512x512 (F0,B0 adjacent for memset)
constexpr size_t SH_HENCB0 = SH_HENCF0 + (size_t)B_*HE_;
constexpr size_t SH_HENCF1 = SH_HENCB0 + (size_t)B_*HE_;
constexpr size_t SH_HENCB1 = SH_HENCF1 + (size_t)B_*HE_;
constexpr size_t SH_HS     = SH_HENCB1 + (size_t)B_*HE_;       // 512x128x2048
constexpr size_t HS_SHORTS = (size_t)B_*T_*HD_;

__device__ __forceinline__ float sigm(float x) { return 1.f / (1.f + expf(-x)); }

__device__ __forceinline__ u16 f2bf(float x) {
    union { float f; uint32_t u; } v; v.f = x;
    uint32_t r = v.u + 0x7fffu + ((v.u >> 16) & 1u);
    return (u16)(r >> 16);
}

using bf16x8 = __attribute__((ext_vector_type(8))) short;
using f32x4  = __attribute__((ext_vector_type(4))) float;

__device__ __forceinline__ void gldl16(const void* g, void* l) {
    __builtin_amdgcn_global_load_lds(
        (const __attribute__((address_space(1))) unsigned int*)g,
        (__attribute__((address_space(3))) unsigned int*)l, 16, 0, 0);
}

// ======================================================================================
// Persistent decoder: 128 LSTM steps in one cooperative kernel.
// W gate-interleaved (row n' = 4h+gate). Tile 64(M)x128(N'), grid 512 = 64 n-tiles(fast)
// x 8 m-tiles = 2 blocks/CU. c in registers for all 128 steps; 1 grid.sync per step.
// ======================================================================================
__global__ __launch_bounds__(256, 2) void dec_persist(
    const u16* __restrict__ Wil, const float* __restrict__ zwil,
    const float* __restrict__ wxil, const float* __restrict__ data,
    const float* __restrict__ c0, u16* __restrict__ h0buf,
    u16* __restrict__ h1buf, u16* __restrict__ hs)
{
    cg::grid_group grd = cg::this_grid();
    const int nt = blockIdx.x & 63, mt = blockIdx.x >> 6;
    const int n0 = nt * 128, m0 = mt * 64;
    const int tid = threadIdx.x, lane = tid & 63, wave = tid >> 6, wn = wave << 5;
    const int fr = lane & 15, fk = lane >> 4;
    const int cr = fk << 2, cc = lane & 15;
    const bool g0 = (lane & 3) == 0;
    const int lb = lane & ~3;

    __shared__ __align__(16) u16 As[64 * 32];
    __shared__ __align__(16) u16 Ws[128 * 32];
    const int sr = tid >> 2, sk = (tid & 3) << 3;
    const u16* gw0 = Wil + (size_t)(n0 + sr) * 2048 + sk;
    const u16* gw1 = gw0 + (size_t)64 * 2048;
    u16* la = As + tid * 8;
    u16* lw0 = Ws + tid * 8;
    u16* lw1 = lw0 + 2048;

    // c state in registers (meaningful on gate-0 lanes only)
    float c_reg[4][2][4];
    if (g0) {
#pragma unroll
        for (int i = 0; i < 4; ++i)
#pragma unroll
            for (int j = 0; j < 2; ++j)
#pragma unroll
                for (int r = 0; r < 4; ++r)
                    c_reg[i][j][r] = c0[(size_t)(m0 + i * 16 + cr + r) * 2048
                                        + ((n0 + wn + j * 16 + cc) >> 2)];
    }

    for (int t = 0; t < 128; ++t) {
        const u16* hin = (t & 1) ? h1buf : h0buf;
        u16* hout = (t & 1) ? h0buf : h1buf;
        const u16* ga = hin + (size_t)(m0 + sr) * 2048 + sk;
        f32x4 acc[4][2] = {};
        for (int k0 = 0; k0 < 2048; k0 += 32) {
            gldl16(ga + k0, la);
            gldl16(gw0 + k0, lw0);
            gldl16(gw1 + k0, lw1);
            __syncthreads();
            bf16x8 af[4], wf[2];
#pragma unroll
            for (int i = 0; i < 4; ++i)
                af[i] = *reinterpret_cast<const bf16x8*>(&As[(i * 16 + fr) * 32 + fk * 8]);
#pragma unroll
            for (int j = 0; j < 2; ++j)
                wf[j] = *reinterpret_cast<const bf16x8*>(&Ws[(wn + j * 16 + fr) * 32 + fk * 8]);
#pragma unroll
            for (int i = 0; i < 4; ++i)
#pragma unroll
                for (int j = 0; j < 2; ++j)
                    acc[i][j] = __builtin_amdgcn_mfma_f32_16x16x32_bf16(af[i], wf[j], acc[i][j], 0, 0, 0);
            __syncthreads();
        }
        // fused LSTM pointwise epilogue (coalesced zwil/wxil reads; gate gather via shfl)
#pragma unroll
        for (int i = 0; i < 4; ++i) {
#pragma unroll
            for (int r = 0; r < 4; ++r) {
                int m = m0 + i * 16 + cr + r;
                float x0 = data[m * 258 + t * 2 + 0];
                float x1 = data[m * 258 + t * 2 + 1];
#pragma unroll
                for (int j = 0; j < 2; ++j) {
                    int np = n0 + wn + j * 16 + cc;
                    float v = acc[i][j][r] + zwil[(size_t)m * 8192 + np]
                              + x0 * wxil[np] + x1 * wxil[8192 + np];
                    float gi = __shfl(v, lb);
                    float gf = __shfl(v, lb | 1);
                    float gG = __shfl(v, lb | 2);
                    float go = __shfl(v, lb | 3);
                    if (g0) {
                        float c2 = sigm(gf) * c_reg[i][j][r] + sigm(gi) * tanhf(gG);
                        float h2 = sigm(go) * tanhf(c2);
                        c_reg[i][j][r] = c2;
                        u16 hv = f2bf(h2);
                        int h = np >> 2;
                        hout[(size_t)m * 2048 + h] = hv;
                        hs[(size_t)m * (T_ * HD_) + (size_t)t * HD_ + h] = hv;
                    }
                }
            }
        }
        __threadfence();
        grd.sync();
    }
}

// ======================================================================================
// Persistent encoder: both dirs, masked. 256 blocks = 16 n-tiles(fast) x 8 m-tiles x 2.
// h and c both register-resident; bf16 h written每 step for next GEMM; fp32 hT at end.
// ======================================================================================
__global__ __launch_bounds__(256, 2) void enc_persist(
    const u16* __restrict__ WF, const u16* __restrict__ WB,
    const float* __restrict__ ihb,   // [dir][3][2048]: bias, wih0, wih1 (interleaved n')
    const float* __restrict__ data, const int* __restrict__ lengths,
    u16* __restrict__ hF0, u16* __restrict__ hF1,
    u16* __restrict__ hB0, u16* __restrict__ hB1,
    float* __restrict__ hFout, float* __restrict__ hBout)
{
    cg::grid_group grd = cg::this_grid();
    const int nt = blockIdx.x & 15;
    const int mt = (blockIdx.x >> 4) & 7;
    const int dir = blockIdx.x >> 7;
    const int n0 = nt * 128, m0 = mt * 64;
    const u16* W = dir ? WB : WF;
    const float* bIl  = ihb + (size_t)dir * 6144;
    const float* w0Il = bIl + 2048;
    const float* w1Il = bIl + 4096;
    u16* e0 = dir ? hB0 : hF0;
    u16* e1 = dir ? hB1 : hF1;
    float* hOut = dir ? hBout : hFout;

    const int tid = threadIdx.x, lane = tid & 63, wave = tid >> 6, wn = wave << 5;
    const int fr = lane & 15, fk = lane >> 4;
    const int cr = fk << 2, cc = lane & 15;
    const bool g0 = (lane & 3) == 0;
    const int lb = lane & ~3;

    __shared__ __align__(16) u16 As[64 * 32];
    __shared__ __align__(16) u16 Ws[128 * 32];
    const int sr = tid >> 2, sk = (tid & 3) << 3;
    const u16* gw0 = W + (size_t)(n0 + sr) * 512 + sk;
    const u16* gw1 = gw0 + (size_t)64 * 512;
    u16* la = As + tid * 8;
    u16* lw0 = Ws + tid * 8;
    u16* lw1 = lw0 + 2048;

    int Lr[4][4];
#pragma unroll
    for (int i = 0; i < 4; ++i)
#pragma unroll
        for (int r = 0; r < 4; ++r) {
            int L = lengths[m0 + i * 16 + cr + r];
            Lr[i][r] = L < 1 ? 1 : (L > 128 ? 128 : L);
        }

    float c_reg[4][2][4] = {};
    float h_reg[4][2][4] = {};

    for (int t = 0; t < 128; ++t) {
        const u16* hin = (t & 1) ? e1 : e0;
        u16* hout = (t & 1) ? e0 : e1;
        const u16* ga = hin + (size_t)(m0 + sr) * 512 + sk;
        f32x4 acc[4][2] = {};
        for (int k0 = 0; k0 < 512; k0 += 32) {
            gldl16(ga + k0, la);
            gldl16(gw0 + k0, lw0);
            gldl16(gw1 + k0, lw1);
            __syncthreads();
            bf16x8 af[4], wf[2];
#pragma unroll
            for (int i = 0; i < 4; ++i)
                af[i] = *reinterpret_cast<const bf16x8*>(&As[(i * 16 + fr) * 32 + fk * 8]);
#pragma unroll
            for (int j = 0; j < 2; ++j)
                wf[j] = *reinterpret_cast<const bf16x8*>(&Ws[(wn + j * 16 + fr) * 32 + fk * 8]);
#pragma unroll
            for (int i = 0; i < 4; ++i)
#pragma unroll
                for (int j = 0; j < 2; ++j)
                    acc[i][j] = __builtin_amdgcn_mfma_f32_16x16x32_bf16(af[i], wf[j], acc[i][j], 0, 0, 0);
            __syncthreads();
        }
#pragma unroll
        for (int i = 0; i < 4; ++i) {
#pragma unroll
            for (int r = 0; r < 4; ++r) {
                int m = m0 + i * 16 + cr + r;
                int L = Lr[i][r];
                bool act = t < L;
                int row = dir ? (L - 1 - t) : t;
                if (row < 0) row = 0;
                float x0 = data[m * 258 + (row + 1) * 2 + 0];
                float x1 = data[m * 258 + (row + 1) * 2 + 1];
#pragma unroll
                for (int j = 0; j < 2; ++j) {
                    int np = n0 + wn + j * 16 + cc;
                    float v = acc[i][j][r] + bIl[np] + x0 * w0Il[np] + x1 * w1Il[np];
                    float gi = __shfl(v, lb);
                    float gf = __shfl(v, lb | 1);
                    float gG = __shfl(v, lb | 2);
                    float go = __shfl(v, lb | 3);
                    if (g0) {
                        if (act) {
                            float c2 = sigm(gf) * c_reg[i][j][r] + sigm(gi) * tanhf(gG);
                            float h2 = sigm(go) * tanhf(c2);
                            c_reg[i][j][r] = c2;
                            h_reg[i][j][r] = h2;
                        }
                        hout[(size_t)m * 512 + (np >> 2)] = f2bf(h_reg[i][j][r]);
                    }
                }
            }
        }
        __threadfence();
        grd.sync();
    }
    // final fp32 hT for the latent projection
    if (g0) {
#pragma unroll
        for (int i = 0; i < 4; ++i)
#pragma unroll
            for (int r = 0; r < 4; ++r) {
                int m = m0 + i * 16 + cr + r;
#pragma unroll
                for (int j = 0; j < 2; ++j) {
                    int np = n0 + wn + j * 16 + cc;
                    hOut[(size_t)m * 512 + (np >> 2)] = h_reg[i][j][r];
                }
            }
    }
}

// ================= plain bf16 MFMA GEMM, 128x128 tile (projection + fallback) ===========
__device__ __forceinline__ void gemm_mfma_body(
    const u16* __restrict__ A, const u16* __restrict__ W,
    const float* __restrict__ bias, float* __restrict__ C,
    int Kd, int lda, int ldw, int ldc, int nmax, int m0, int n0)
{
    __shared__ __align__(16) u16 As[128 * 32];
    __shared__ __align__(16) u16 Ws[128 * 32];
    const int tid = threadIdx.x;
    const int lane = tid & 63;
    const int wave = tid >> 6;
    const int wm = (wave & 1) << 6, wn = (wave >> 1) << 6;
    const int fr = lane & 15, fk = lane >> 4;
    f32x4 acc[4][4] = {};

    const int sr = tid >> 2, sk = (tid & 3) << 3;
    const u16* ga0 = A + (size_t)(m0 + sr) * lda + sk;
    const u16* ga1 = ga0 + (size_t)64 * lda;
    const u16* gw0 = W + (size_t)(n0 + sr) * ldw + sk;
    const u16* gw1 = gw0 + (size_t)64 * ldw;
    u16* la0 = As + tid * 8;
    u16* la1 = la0 + 2048;
    u16* lw0 = Ws + tid * 8;
    u16* lw1 = lw0 + 2048;

    for (int k0 = 0; k0 < Kd; k0 += 32) {
        gldl16(ga0 + k0, la0);
        gldl16(ga1 + k0, la1);
        gldl16(gw0 + k0, lw0);
        gldl16(gw1 + k0, lw1);
        __syncthreads();
        bf16x8 af[4], wf[4];
#pragma unroll
        for (int i = 0; i < 4; ++i)
            af[i] = *reinterpret_cast<const bf16x8*>(&As[(wm + i * 16 + fr) * 32 + fk * 8]);
#pragma unroll
        for (int j = 0; j < 4; ++j)
            wf[j] = *reinterpret_cast<const bf16x8*>(&Ws[(wn + j * 16 + fr) * 32 + fk * 8]);
#pragma unroll
        for (int i = 0; i < 4; ++i)
#pragma unroll
            for (int j = 0; j < 4; ++j)
                acc[i][j] = __builtin_amdgcn_mfma_f32_16x16x32_bf16(af[i], wf[j], acc[i][j], 0, 0, 0);
        __syncthreads();
    }

    const int cr = (lane >> 4) << 2, cc = lane & 15;
#pragma unroll
    for (int j = 0; j < 4; ++j) {
        int n = n0 + wn + j * 16 + cc;
        if (n < nmax) {
            float bv = bias ? bias[n] : 0.f;
#pragma unroll
            for (int i = 0; i < 4; ++i) {
                int m = m0 + wm + i * 16 + cr;
                float* cp = C + (size_t)m * ldc + n;
#pragma unroll
                for (int r = 0; r < 4; ++r)
                    cp[(size_t)r * ldc] = acc[i][j][r] + bv;
            }
        }
    }
}

__global__ __launch_bounds__(256) void gemm_bf16_k(
    const u16* __restrict__ A, const u16* __restrict__ W,
    const float* __restrict__ bias, float* __restrict__ C,
    int Kd, int lda, int ldw, int ldc, int nmax)
{
    gemm_mfma_body(A, W, bias, C, Kd, lda, ldw, ldc, nmax,
                   blockIdx.x * 128, blockIdx.y * 128);
}

__global__ __launch_bounds__(256) void gemm_enc_mfma(
    const u16* __restrict__ hF, const u16* __restrict__ hB,
    const u16* __restrict__ Wf, const u16* __restrict__ Wb,
    float* __restrict__ g)
{
    const u16* A = blockIdx.z ? hB : hF;
    const u16* W = blockIdx.z ? Wb : Wf;
    float* C = g + (size_t)blockIdx.z * ((size_t)B_ * 4 * HE_);
    gemm_mfma_body(A, W, nullptr, C, HE_, HE_, HE_, 4 * HE_, 4 * HE_,
                   blockIdx.y * 128, blockIdx.x * 128);
}

// Fallback decoder GEMM (R4)
__global__ __launch_bounds__(256) void gemm_dec64(
    const u16* __restrict__ A, const u16* __restrict__ W, float* __restrict__ C)
{
    __shared__ __align__(16) u16 As[64 * 32];
    __shared__ __align__(16) u16 Ws[128 * 32];
    const int tid = threadIdx.x, lane = tid & 63, wave = tid >> 6;
    const int n0 = blockIdx.x * 128, m0 = blockIdx.y * 64;
    const int wn = wave << 5;
    const int fr = lane & 15, fk = lane >> 4;
    f32x4 acc[4][2] = {};
    const int sr = tid >> 2, sk = (tid & 3) << 3;
    const u16* ga  = A + (size_t)(m0 + sr) * 2048 + sk;
    const u16* gw0 = W + (size_t)(n0 + sr) * 2048 + sk;
    const u16* gw1 = gw0 + (size_t)64 * 2048;
    u16* la  = As + tid * 8;
    u16* lw0 = Ws + tid * 8;
    u16* lw1 = lw0 + 2048;
    for (int k0 = 0; k0 < 2048; k0 += 32) {
        gldl16(ga + k0, la);
        gldl16(gw0 + k0, lw0);
        gldl16(gw1 + k0, lw1);
        __syncthreads();
        bf16x8 af[4], wf[2];
#pragma unroll
        for (int i = 0; i < 4; ++i)
            af[i] = *reinterpret_cast<const bf16x8*>(&As[(i * 16 + fr) * 32 + fk * 8]);
#pragma unroll
        for (int j = 0; j < 2; ++j)
            wf[j] = *reinterpret_cast<const bf16x8*>(&Ws[(wn + j * 16 + fr) * 32 + fk * 8]);
#pragma unroll
        for (int i = 0; i < 4; ++i)
#pragma unroll
            for (int j = 0; j < 2; ++j)
                acc[i][j] = __builtin_amdgcn_mfma_f32_16x16x32_bf16(af[i], wf[j], acc[i][j], 0, 0, 0);
        __syncthreads();
    }
    const int cr = (lane >> 4) << 2, cc = lane & 15;
#pragma unroll
    for (int i = 0; i < 4; ++i)
#pragma unroll
        for (int j = 0; j < 2; ++j) {
            int n = n0 + wn + j * 16 + cc;
            float* cp = C + (size_t)(m0 + i * 16 + cr) * 8192 + n;
#pragma unroll
            for (int r = 0; r < 4; ++r)
                cp[(size_t)r * 8192] = acc[i][j][r];
        }
}

// ================= fp32 tiled GEMM (small latent GEMMs) =================
__device__ __forceinline__ void gemm_body(
    const float* __restrict__ A, const float* __restrict__ W,
    const float* __restrict__ bias, float* __restrict__ C,
    int N, int Kd, int lda, int aoff, int ldw, int woff,
    int ldc, int coff, int m0, int n0)
{
    __shared__ __align__(16) float As[16][68];
    __shared__ __align__(16) float Ws[16][68];
    const int tid = threadIdx.x;
    const int tx = tid & 15, ty = tid >> 4;
    float acc[4][4] = {};
    for (int k0 = 0; k0 < Kd; k0 += 16) {
#pragma unroll
        for (int i = 0; i < 4; ++i) {
            int e = tid + i * 256;
            int mm = e >> 4, kk = e & 15;
            As[kk][mm] = A[(size_t)(m0 + mm) * lda + aoff + k0 + kk];
        }
#pragma unroll
        for (int i = 0; i < 4; ++i) {
            int e = tid + i * 256;
            int nn = e >> 4, kk = e & 15;
            int n = n0 + nn;
            Ws[kk][nn] = (n < N) ? W[(size_t)n * ldw + woff + k0 + kk] : 0.f;
        }
        __syncthreads();
#pragma unroll
        for (int kk = 0; kk < 16; ++kk) {
            float4 a = *reinterpret_cast<const float4*>(&As[kk][ty * 4]);
            float4 w = *reinterpret_cast<const float4*>(&Ws[kk][tx * 4]);
            float av[4] = {a.x, a.y, a.z, a.w};
            float wv[4] = {w.x, w.y, w.z, w.w};
#pragma unroll
            for (int i = 0; i < 4; ++i)
#pragma unroll
                for (int j = 0; j < 4; ++j)
                    acc[i][j] = fmaf(av[i], wv[j], acc[i][j]);
        }
        __syncthreads();
    }
#pragma unroll
    for (int i = 0; i < 4; ++i) {
        int m = m0 + ty * 4 + i;
#pragma unroll
        for (int j = 0; j < 4; ++j) {
            int n = n0 + tx * 4 + j;
            if (n < N) {
                float v = acc[i][j];
                if (bias) v += bias[n];
                C[(size_t)m * ldc + coff + n] = v;
            }
        }
    }
}

__global__ __launch_bounds__(256) void gemm_k(
    const float* __restrict__ A, const float* __restrict__ W,
    const float* __restrict__ bias, float* __restrict__ C,
    int N, int Kd, int lda, int aoff, int ldw, int woff, int ldc, int coff)
{
    gemm_body(A, W, bias, C, N, Kd, lda, aoff, ldw, woff, ldc, coff,
              blockIdx.x * 64, blockIdx.y * 64);
}

// ================= conversion / prep kernels =================
__global__ __launch_bounds__(256) void conv_bf16(
    const float* __restrict__ src, u16* __restrict__ dst, int n)
{
    int stride = gridDim.x * 256;
    for (int i = blockIdx.x * 256 + threadIdx.x; i < n; i += stride)
        dst[i] = f2bf(src[i]);
}

// decoder W interleaved: dst[(4h+g)*2048+k] = bf16(src[(g*2048+h)*2048+k])
__global__ __launch_bounds__(256) void conv_wdec_il(
    const float* __restrict__ src, u16* __restrict__ dst)
{
    int row = blockIdx.x;
    int g = row >> 11, h = row & 2047;
    size_t so = (size_t)row * 2048, dofs = (size_t)(h * 4 + g) * 2048;
    for (int k = threadIdx.x; k < 2048; k += 256)
        dst[dofs + k] = f2bf(src[so + k]);
}

// encoder W interleaved, both dirs
__global__ __launch_bounds__(256) void conv_wenc_il(
    const float* __restrict__ srcF, const float* __restrict__ srcB,
    u16* __restrict__ dstF, u16* __restrict__ dstB)
{
    int row = blockIdx.x & 2047;
    int dir = blockIdx.x >> 11;
    const float* s = dir ? srcB : srcF;
    u16* d = dir ? dstB : dstF;
    int g = row >> 9, h = row & 511;
    size_t so = (size_t)row * 512, dofs = (size_t)(h * 4 + g) * 512;
    for (int k = threadIdx.x; k < 512; k += 256)
        d[dofs + k] = f2bf(s[so + k]);
}

__global__ __launch_bounds__(256) void conv_outw(
    const float* __restrict__ w, u16* __restrict__ dst)
{
    int i = blockIdx.x * 256 + threadIdx.x;
    int row = i >> 11, col = i & 2047;
    dst[i] = (row < NOUT_) ? f2bf(w[(size_t)row * HD_ + col]) : (u16)0;
}

// encoder interleaved bias + Wih cols: ihb[dir][{b,w0,w1}][np]
__global__ __launch_bounds__(256) void prep_enc_ihb(
    const float* __restrict__ WihF, const float* __restrict__ bF,
    const float* __restrict__ WihB, const float* __restrict__ bB,
    float* __restrict__ ihb)
{
    int i = blockIdx.x * 256 + threadIdx.x;   // 2*2048
    if (i >= 4096) return;
    int dir = i >> 11, np = i & 2047;
    int gate = np & 3, h = np >> 2;
    int no = gate * 512 + h;
    const float* Wih = dir ? WihB : WihF;
    const float* b = dir ? bB : bF;
    float* o = ihb + (size_t)dir * 6144;
    o[np] = b[no];
    o[2048 + np] = Wih[2 * no];
    o[4096 + np] = Wih[2 * no + 1];
}

// zW -> interleaved zwil (writes coalesced)
__global__ __launch_bounds__(256) void zw_il(
    const float* __restrict__ zw, float* __restrict__ zwil)
{
    int i = blockIdx.x * 256 + threadIdx.x;   // 512*8192
    int m = i >> 13, np = i & 8191;
    int gate = np & 3, h = np >> 2;
    zwil[i] = zw[(size_t)m * 8192 + gate * 2048 + h];
}

// interleaved wx for decoder epilogue
__global__ __launch_bounds__(256) void prep_wx_il(
    const float* __restrict__ Wih, float* __restrict__ wxil)
{
    int np = blockIdx.x * 256 + threadIdx.x;   // 8192
    int gate = np & 3, h = np >> 2;
    size_t row = (size_t)(gate * 2048 + h) * 133;
    wxil[np] = Wih[row];
    wxil[8192 + np] = Wih[row + 1];
}

// plain wx (fallback)
__global__ __launch_bounds__(256) void prep_wx(
    const float* __restrict__ Wih, float* __restrict__ wx)
{
    int j = blockIdx.x * 256 + threadIdx.x;
    wx[j] = Wih[(size_t)j * 133];
    wx[8192 + j] = Wih[(size_t)j * 133 + 1];
}

// ================= pointwise kernels =================
__global__ __launch_bounds__(256) void point_enc(
    const float* __restrict__ g, const float* __restrict__ data,
    const float* __restrict__ Wih_f, const float* __restrict__ bf,
    const float* __restrict__ Wih_b, const float* __restrict__ bb,
    const int* __restrict__ lengths,
    float* __restrict__ hF, float* __restrict__ cF,
    float* __restrict__ hB, float* __restrict__ cB,
    u16* __restrict__ hFb, u16* __restrict__ hBb, int t)
{
    int idx = blockIdx.x * 256 + threadIdx.x;
    int dir = idx >> 18;
    int r = idx & ((1 << 18) - 1);
    int b = r >> 9, n = r & 511;
    int L = lengths[b]; L = L < 1 ? 1 : (L > 128 ? 128 : L);
    if (t >= L) return;
    const float* gp = g + (size_t)dir * ((size_t)B_ * 4 * HE_) + (size_t)b * (4 * HE_);
    float gi = gp[n], gf = gp[HE_ + n], gg = gp[2 * HE_ + n], go = gp[3 * HE_ + n];
    int row = dir ? (L - 1 - t) : t;
    float x0 = data[b * 258 + (row + 1) * 2 + 0];
    float x1 = data[b * 258 + (row + 1) * 2 + 1];
    const float* Wih = dir ? Wih_b : Wih_f;
    const float* bias = dir ? bb : bf;
    gi += bias[n]          + x0 * Wih[2 * n]              + x1 * Wih[2 * n + 1];
    gf += bias[HE_ + n]    + x0 * Wih[2 * (HE_ + n)]      + x1 * Wih[2 * (HE_ + n) + 1];
    gg += bias[2*HE_ + n]  + x0 * Wih[2 * (2*HE_ + n)]    + x1 * Wih[2 * (2*HE_ + n) + 1];
    go += bias[3*HE_ + n]  + x0 * Wih[2 * (3*HE_ + n)]    + x1 * Wih[2 * (3*HE_ + n) + 1];
    float* h = dir ? hB : hF;
    float* c = dir ? cB : cF;
    u16* hb = dir ? hBb : hFb;
    int o = b * HE_ + n;
    float c2 = sigm(gf) * c[o] + sigm(gi) * tanhf(gg);
    float h2 = sigm(go) * tanhf(c2);
    h[o] = h2; c[o] = c2; hb[o] = f2bf(h2);
}

__global__ __launch_bounds__(256) void copy_hn(
    const float* __restrict__ hF, const float* __restrict__ hB, float* __restrict__ hn)
{
    int i = blockIdx.x * 256 + threadIdx.x;
    int b = i >> 10, j = i & 1023;
    hn[i] = (j < 512) ? hF[b * 512 + j] : hB[b * 512 + j - 512];
}

__global__ __launch_bounds__(256) void point_z(
    const float* __restrict__ zmzl, const float* __restrict__ eps,
    float* __restrict__ ozm, float* __restrict__ ozl, float* __restrict__ z)
{
    int i = blockIdx.x * 256 + threadIdx.x;
    int b = i >> 7, j = i & 127;
    float zm = zmzl[b * 256 + j], zl = zmzl[b * 256 + 128 + j];
    ozm[i] = zm; ozl[i] = zl;
    z[i] = zm + expf(0.5f * zl) * eps[i];
}

__global__ __launch_bounds__(256) void point_init(
    const float* __restrict__ g, float* __restrict__ h, float* __restrict__ c,
    u16* __restrict__ hb)
{
    int i = blockIdx.x * 256 + threadIdx.x;
    int b = i >> 11, n = i & 2047;
    float hv = tanhf(g[(size_t)b * 4096 + n]);
    h[i] = hv; hb[i] = f2bf(hv);
    c[i] = tanhf(g[(size_t)b * 4096 + 2048 + n]);
}

__global__ __launch_bounds__(256) void point_dec(
    const float* __restrict__ g, const float* __restrict__ zW,
    const float* __restrict__ data, const float* __restrict__ wx,
    float* __restrict__ h, float* __restrict__ c,
    u16* __restrict__ hb, u16* __restrict__ hs, int t)
{
    int idx = blockIdx.x * 256 + threadIdx.x;
    int b = idx >> 11, n = idx & 2047;
    float x0 = data[b * 258 + t * 2 + 0];
    float x1 = data[b * 258 + t * 2 + 1];
    const float* gp = g + (size_t)b * 8192;
    const float* zp = zW + (size_t)b * 8192;
    int j0 = n, j1 = 2048 + n, j2 = 4096 + n, j3 = 6144 + n;
    float gi = gp[j0] + zp[j0] + x0 * wx[j0] + x1 * wx[8192 + j0];
    float gf = gp[j1] + zp[j1] + x0 * wx[j1] + x1 * wx[8192 + j1];
    float gg = gp[j2] + zp[j2] + x0 * wx[j2] + x1 * wx[8192 + j2];
    float go = gp[j3] + zp[j3] + x0 * wx[j3] + x1 * wx[8192 + j3];
    float c2 = sigm(gf) * c[idx] + sigm(gi) * tanhf(gg);
    float h2 = sigm(go) * tanhf(c2);
    h[idx] = h2; c[idx] = c2;
    u16 hv = f2bf(h2);
    hb[idx] = hv;
    if (hs) hs[(size_t)b * (T_ * HD_) + (size_t)t * HD_ + n] = hv;
}

__global__ __launch_bounds__(256) void proj_step(
    const float* __restrict__ h, const float* __restrict__ out_W,
    const float* __restrict__ out_b, float* __restrict__ out, int t)
{
    __shared__ __align__(16) float sh[2048];
    int b = blockIdx.x;
    for (int i = threadIdx.x; i < 2048; i += 256) sh[i] = h[(size_t)b * 2048 + i];
    __syncthreads();
    int n = threadIdx.x >> 1, half = threadIdx.x & 1;
    if (n >= NOUT_) return;
    const float4* w4 = reinterpret_cast<const float4*>(out_W + (size_t)n * 2048 + half * 1024);
    const float4* h4 = reinterpret_cast<const float4*>(sh + half * 1024);
    float s = 0.f;
#pragma unroll 4
    for (int k = 0; k < 256; ++k) {
        float4 a = h4[k], w = w4[k];
        s += a.x * w.x + a.y * w.y + a.z * w.z + a.w * w.w;
    }
    s += __shfl_xor(s, 1);
    if (half == 0) out[(size_t)b * (T_ * NOUT_) + (size_t)t * NOUT_ + n] = s + out_b[n];
}

extern "C" void kernel_launch(void* const* d_in, const int* in_sizes, int n_in,
                              void* d_out, int out_size, void* d_ws, size_t ws_size,
                              hipStream_t stream)
{
    const float* data      = (const float*)d_in[0];
    const float* eps       = (const float*)d_in[1];
    const float* enc_Wih_f = (const float*)d_in[2];
    const float* enc_Whh_f = (const float*)d_in[3];
    const float* enc_b_f   = (const float*)d_in[4];
    const float* enc_Wih_b = (const float*)d_in[5];
    const float* enc_Whh_b = (const float*)d_in[6];
    const float* enc_b_b   = (const float*)d_in[7];
    const float* enc_out_W = (const float*)d_in[8];
    const float* enc_out_b = (const float*)d_in[9];
    const float* init_W    = (const float*)d_in[10];
    const float* init_b    = (const float*)d_in[11];
    const float* dec_Wih   = (const float*)d_in[12];
    const float* dec_Whh   = (const float*)d_in[13];
    const float* dec_b     = (const float*)d_in[14];
    const float* out_W     = (const float*)d_in[15];
    const float* out_b     = (const float*)d_in[16];
    const int*   lengths   = (const int*)d_in[17];

    float* ws  = (float*)d_ws;
    float* out = (float*)d_out;
    float* hF = ws + OFF_HF, *cF = ws + OFF_CF, *hB = ws + OFF_HB, *cB = ws + OFF_CB;
    float* hd = ws + OFF_HD, *cd = ws + OFF_CD;
    float* zW = ws + OFF_ZW, *g = ws + OFF_G, *hn = ws + OFF_HN;
    float* zmzl = ws + OFF_ZMZL, *z = ws + OFF_Z, *wx = ws + OFF_WX;
    float* zwil = g;                 // persistent path reuses g region
    float* ihb  = hn;                // persistent path reuses hn head (12288 floats)
    u16* bw = (u16*)(ws + BASE_FLOATS);
    u16* wbDec  = bw + SH_WDEC, *wbEncF = bw + SH_WENCF, *wbEncB = bw + SH_WENCB;
    u16* wbOut  = bw + SH_OUTW;
    u16* hD0 = bw + SH_HDEC0, *hD1 = bw + SH_HDEC1;
    u16* hEF0 = bw + SH_HENCF0, *hEB0 = bw + SH_HENCB0;
    u16* hEF1 = bw + SH_HENCF1, *hEB1 = bw + SH_HENCB1;
    u16* hs = bw + SH_HS;
    float* ozm = out + (size_t)B_ * T_ * NOUT_;
    float* ozl = ozm + (size_t)B_ * Z_;

    bool big = ws_size >= BASE_FLOATS * sizeof(float) + (SH_HS + HS_SHORTS) * sizeof(u16);
    int occD = 0, occE = 0;
    hipOccupancyMaxActiveBlocksPerMultiprocessor(&occD, dec_persist, 256, 0);
    hipOccupancyMaxActiveBlocksPerMultiprocessor(&occE, enc_persist, 256, 0);
    bool use_p = big && occD >= 2 && occE >= 1;

    if (use_p) {
        // ---- prep (interleaved layouts)
        conv_wdec_il<<<8192, 256, 0, stream>>>(dec_Whh, wbDec);
        conv_wenc_il<<<4096, 256, 0, stream>>>(enc_Whh_f, enc_Whh_b, wbEncF, wbEncB);
        conv_outw<<<1024, 256, 0, stream>>>(out_W, wbOut);
        prep_enc_ihb<<<16, 256, 0, stream>>>(enc_Wih_f, enc_b_f, enc_Wih_b, enc_b_b, ihb);
        hipMemsetAsync(hEF0, 0, (size_t)2 * B_ * HE_ * sizeof(u16), stream);

        // ---- encoder: one cooperative kernel, 128 steps
        void* ea[] = { (void*)&wbEncF, (void*)&wbEncB, (void*)&ihb, (void*)&data,
                       (void*)&lengths, (void*)&hEF0, (void*)&hEF1, (void*)&hEB0,
                       (void*)&hEB1, (void*)&hF, (void*)&hB };
        hipLaunchCooperativeKernel(enc_persist, dim3(256), dim3(256), ea, 0, stream);

        // ---- latent
        copy_hn<<<2048, 256, 0, stream>>>(hF, hB, hn);
        gemm_k<<<dim3(8, 4), 256, 0, stream>>>(hn, enc_out_W, enc_out_b, zmzl,
                                               256, 1024, 1024, 0, 1024, 0, 256, 0);
        point_z<<<256, 256, 0, stream>>>(zmzl, eps, ozm, ozl, z);
        gemm_k<<<dim3(8, 64), 256, 0, stream>>>(z, init_W, init_b, zW,
                                                4096, 128, 128, 0, 128, 0, 4096, 0);
        point_init<<<4096, 256, 0, stream>>>(zW, hd, cd, hD0);
        gemm_k<<<dim3(8, 128), 256, 0, stream>>>(z, dec_Wih, dec_b, zW,
                                                 8192, 128, 128, 0, 133, 5, 8192, 0);
        zw_il<<<16384, 256, 0, stream>>>(zW, zwil);
        prep_wx_il<<<32, 256, 0, stream>>>(dec_Wih, ws + OFF_WX);

        // ---- decoder: one cooperative kernel, 128 steps
        void* da[] = { (void*)&wbDec, (void*)&zwil, (void*)&wx, (void*)&data,
                       (void*)&cd, (void*)&hD0, (void*)&hD1, (void*)&hs };
        hipLaunchCooperativeKernel(dec_persist, dim3(512), dim3(256), da, 0, stream);

        // ---- projection
        gemm_bf16_k<<<dim3(512, 1), 256, 0, stream>>>(hs, wbOut, out_b, out,
                                                      2048, 2048, 2048, 123, 123);
    } else {
        // ================= fallback: R4 path =================
        conv_bf16<<<4096, 256, 0, stream>>>(dec_Whh, wbDec, 4 * HD_ * HD_);
        conv_bf16<<<1024, 256, 0, stream>>>(enc_Whh_f, wbEncF, 4 * HE_ * HE_);
        conv_bf16<<<1024, 256, 0, stream>>>(enc_Whh_b, wbEncB, 4 * HE_ * HE_);
        conv_outw<<<1024, 256, 0, stream>>>(out_W, wbOut);
        hipMemsetAsync(ws, 0, (size_t)4 * B_ * HE_ * sizeof(float), stream);
        hipMemsetAsync(hEF0, 0, (size_t)2 * B_ * HE_ * sizeof(u16), stream);

        for (int t = 0; t < T_; ++t) {
            gemm_enc_mfma<<<dim3(16, 4, 2), 256, 0, stream>>>(hEF0, hEB0, wbEncF, wbEncB, g);
            point_enc<<<2048, 256, 0, stream>>>(g, data, enc_Wih_f, enc_b_f, enc_Wih_b, enc_b_b,
                                                lengths, hF, cF, hB, cB, hEF0, hEB0, t);
        }
        copy_hn<<<2048, 256, 0, stream>>>(hF, hB, hn);
        gemm_k<<<dim3(8, 4), 256, 0, stream>>>(hn, enc_out_W, enc_out_b, zmzl,
                                               256, 1024, 1024, 0, 1024, 0, 256, 0);
        point_z<<<256, 256, 0, stream>>>(zmzl, eps, ozm, ozl, z);
        gemm_k<<<dim3(8, 64), 256, 0, stream>>>(z, init_W, init_b, g,
                                                4096, 128, 128, 0, 128, 0, 4096, 0);
        point_init<<<4096, 256, 0, stream>>>(g, hd, cd, hD0);
        gemm_k<<<dim3(8, 128), 256, 0, stream>>>(z, dec_Wih, dec_b, zW,
                                                 8192, 128, 128, 0, 133, 5, 8192, 0);
        prep_wx<<<32, 256, 0, stream>>>(dec_Wih, wx);

        u16* hsf = big ? hs : nullptr;
        for (int t = 0; t < T_; ++t) {
            gemm_dec64<<<dim3(64, 8), 256, 0, stream>>>(hD0, wbDec, g);
            point_dec<<<4096, 256, 0, stream>>>(g, zW, data, wx, hd, cd, hD0, hsf, t);
            if (!big) proj_step<<<512, 256, 0, stream>>>(hd, out_W, out_b, out, t);
        }
        if (big) {
            gemm_bf16_k<<<dim3(512, 1), 256, 0, stream>>>(hs, wbOut, out_b, out,
                                                          2048, 2048, 2048, 123, 123);
        }
    }
}